// Round 1
// baseline (644.794 us; speedup 1.0000x reference)
//
#include <hip/hip_runtime.h>
#include <hip/hip_bf16.h>
#include <stdint.h>

using bf16 = __hip_bfloat16;
typedef __attribute__((ext_vector_type(8))) short short8;
typedef __attribute__((ext_vector_type(4))) short short4b;
typedef __attribute__((ext_vector_type(4))) float f32x4;

// Problem constants
// BATCH=4, N=2048, H=8, DK=64, DIM=512, rows = B*N = 8192

__device__ __forceinline__ short8 load8(const bf16* p) {
  return *reinterpret_cast<const short8*>(p);
}
__device__ __forceinline__ short4b load4(const bf16* p) {
  return *reinterpret_cast<const short4b*>(p);
}
__device__ __forceinline__ short f2b(float f) {
  return __builtin_bit_cast(short, __float2bfloat16(f));
}

// ---------------- prep kernels ----------------

__global__ void k_xconv(const float4* __restrict__ x, ushort4* __restrict__ xb) {
  int i = blockIdx.x * 256 + threadIdx.x;  // over 4194304/4
  float4 v = x[i];
  ushort4 o;
  o.x = (unsigned short)__builtin_bit_cast(short, __float2bfloat16(v.x));
  o.y = (unsigned short)__builtin_bit_cast(short, __float2bfloat16(v.y));
  o.z = (unsigned short)__builtin_bit_cast(short, __float2bfloat16(v.z));
  o.w = (unsigned short)__builtin_bit_cast(short, __float2bfloat16(v.w));
  xb[i] = o;
}

__global__ void k_maskpack(const int* __restrict__ mask,
                           unsigned long long* __restrict__ bits) {
  int i = blockIdx.x * 256 + threadIdx.x;  // over 16777216
  unsigned long long w = __ballot(mask[i] != 0);
  if ((threadIdx.x & 63) == 0) bits[i >> 6] = w;
}

// W_{q,k,v}: [h][d][dk] -> Wt [h][dk][d]  (bf16);  W_out: [h][v][e] -> Wot [e][h*64+v]
__global__ void k_wprep(const float* __restrict__ Wq, const float* __restrict__ Wk,
                        const float* __restrict__ Wv, const float* __restrict__ Wo,
                        bf16* __restrict__ Wqt, bf16* __restrict__ Wkt,
                        bf16* __restrict__ Wvt, bf16* __restrict__ Wot) {
  int t = blockIdx.x * 256 + threadIdx.x;  // over 4*262144
  int which = t >> 18, rr = t & 262143;
  if (which < 3) {
    const float* W = (which == 0) ? Wq : ((which == 1) ? Wk : Wv);
    bf16* Wt = (which == 0) ? Wqt : ((which == 1) ? Wkt : Wvt);
    int h = rr >> 15, rem = rr & 32767, dk = rem >> 9, d = rem & 511;
    Wt[rr] = __float2bfloat16(W[(h * 512 + d) * 64 + dk]);
  } else {
    int e = rr >> 9, hv = rr & 511;
    Wot[rr] = __float2bfloat16(Wo[hv * 512 + e]);
  }
}

// ---------------- GEMM core: C[64x64] = A[M][512] * Bt[N][512]^T ----------------
// block = 256 thr (4 waves); wave w computes rows 0..63 x cols w*16..w*16+15.
// MFMA 16x16x32 bf16: A-frag lane: m=lane&15, k=(lane>>4)*8+j ; B-frag: n=lane&15,
// same k ; C: col=lane&15, row=4*(lane>>4)+reg.

__device__ __forceinline__ void gemm64(const bf16* __restrict__ A,
                                       const bf16* __restrict__ Bt,
                                       int rowBase, int colBase, f32x4 acc[4]) {
  const int lane = threadIdx.x & 63;
  const int wave = threadIdx.x >> 6;
  const int g = lane >> 4, r = lane & 15;
  const bf16* aP = A + (size_t)(rowBase + r) * 512 + g * 8;
  const bf16* bP = Bt + (size_t)(colBase + wave * 16 + r) * 512 + g * 8;
#pragma unroll 4
  for (int ks = 0; ks < 16; ++ks) {
    short8 bf = load8(bP + ks * 32);
#pragma unroll
    for (int mt = 0; mt < 4; ++mt) {
      short8 af = load8(aP + (size_t)mt * 16 * 512 + ks * 32);
      acc[mt] = __builtin_amdgcn_mfma_f32_16x16x32_bf16(af, bf, acc[mt], 0, 0, 0);
    }
  }
}

// P1: Q/K projection.  A=Xb[8192][512], Bt=Wt[512(h*64+dk)][512].
// Out layout: [b][h][n][64]
__global__ __launch_bounds__(256) void k_proj_qk(const bf16* __restrict__ Xb,
    const bf16* __restrict__ Wqt, const bf16* __restrict__ Wkt,
    bf16* __restrict__ Qo, bf16* __restrict__ Ko) {
  const bf16* Wt = blockIdx.z ? Wkt : Wqt;
  bf16* Out = blockIdx.z ? Ko : Qo;
  int rowBase = blockIdx.x * 64, colBase = blockIdx.y * 64;
  f32x4 acc[4] = {};
  gemm64(Xb, Wt, rowBase, colBase, acc);
  const int lane = threadIdx.x & 63;
  const int wave = threadIdx.x >> 6;
  const int g = lane >> 4, r = lane & 15;
  int col = colBase + wave * 16 + r;
  int h = col >> 6, dk = col & 63;
#pragma unroll
  for (int mt = 0; mt < 4; ++mt)
#pragma unroll
    for (int rr = 0; rr < 4; ++rr) {
      int row = rowBase + mt * 16 + 4 * g + rr;
      int b = row >> 11, n = row & 2047;
      Out[((size_t)(b * 8 + h) * 2048 + n) * 64 + dk] = __float2bfloat16(acc[mt][rr]);
    }
}

// P2: V projection producing V^T.  A=Wvt[512(h*64+dv)][512], Bt=Xb[8192][512].
// Out layout Vt: [b][h*64+dv][n]
__global__ __launch_bounds__(256) void k_proj_v(const bf16* __restrict__ Wvt,
    const bf16* __restrict__ Xb, bf16* __restrict__ Vt) {
  int rowBase = blockIdx.x * 64, colBase = blockIdx.y * 64;
  f32x4 acc[4] = {};
  gemm64(Wvt, Xb, rowBase, colBase, acc);
  const int lane = threadIdx.x & 63;
  const int wave = threadIdx.x >> 6;
  const int g = lane >> 4, r = lane & 15;
  int col = colBase + wave * 16 + r;  // bn
  int b = col >> 11, n = col & 2047;
#pragma unroll
  for (int mt = 0; mt < 4; ++mt)
#pragma unroll
    for (int rr = 0; rr < 4; ++rr) {
      int hdv = rowBase + mt * 16 + 4 * g + rr;
      Vt[((size_t)b * 512 + hdv) * 2048 + n] = __float2bfloat16(acc[mt][rr]);
    }
}

// P3: output projection. A=O[8192][512(h*64+dv)], Bt=Wot[512(e)][512], out fp32.
__global__ __launch_bounds__(256) void k_proj_out(const bf16* __restrict__ O,
    const bf16* __restrict__ Wot, float* __restrict__ out) {
  int rowBase = blockIdx.x * 64, colBase = blockIdx.y * 64;
  f32x4 acc[4] = {};
  gemm64(O, Wot, rowBase, colBase, acc);
  const int lane = threadIdx.x & 63;
  const int wave = threadIdx.x >> 6;
  const int g = lane >> 4, r = lane & 15;
  int col = colBase + wave * 16 + r;
#pragma unroll
  for (int mt = 0; mt < 4; ++mt)
#pragma unroll
    for (int rr = 0; rr < 4; ++rr) {
      int row = rowBase + mt * 16 + 4 * g + rr;
      out[(size_t)row * 512 + col] = acc[mt][rr];
    }
}

// ---------------- flash attention ----------------
// grid: (bh=32, qt=32); block 256 = 4 waves; wave handles 16 q-rows.
// S^T = K*Q^T so softmax row = lane&15. PV uses permuted-contraction V frags.
__global__ __launch_bounds__(256) void k_attn(const bf16* __restrict__ Q,
    const bf16* __restrict__ K, const bf16* __restrict__ Vt,
    const unsigned long long* __restrict__ MB, bf16* __restrict__ O) {
  const int bh = blockIdx.x;
  const int qt = blockIdx.y;
  const int b = bh >> 3, h = bh & 7;
  const int lane = threadIdx.x & 63;
  const int wave = threadIdx.x >> 6;
  const int g = lane >> 4, r = lane & 15;
  const int qbase = qt * 64 + wave * 16;

  const bf16* Qp = Q + ((size_t)bh * 2048 + qbase + r) * 64;
  short8 qf0 = load8(Qp + g * 8);
  short8 qf1 = load8(Qp + 32 + g * 8);
  const bf16* Kp = K + (size_t)bh * 2048 * 64;
  const bf16* Vp = Vt + (size_t)bh * 64 * 2048;
  const unsigned long long* Mp = MB + ((size_t)b * 2048 + qbase + r) * 32;

  float m_run = -1e30f, l_run = 0.f;
  f32x4 acc[4] = {};

  for (int kt = 0; kt < 32; ++kt) {
    const bf16* Kt = Kp + kt * 64 * 64;
    f32x4 st[4];
#pragma unroll
    for (int kc = 0; kc < 4; ++kc) {
      short8 kf0 = load8(Kt + (kc * 16 + r) * 64 + g * 8);
      short8 kf1 = load8(Kt + (kc * 16 + r) * 64 + 32 + g * 8);
      f32x4 z = {};
      z = __builtin_amdgcn_mfma_f32_16x16x32_bf16(kf0, qf0, z, 0, 0, 0);
      st[kc] = __builtin_amdgcn_mfma_f32_16x16x32_bf16(kf1, qf1, z, 0, 0, 0);
    }
    unsigned long long mw = Mp[kt];
    float s[16];
    float mloc = -1e30f;
#pragma unroll
    for (int kc = 0; kc < 4; ++kc)
#pragma unroll
      for (int rr = 0; rr < 4; ++rr) {
        int kcl = kc * 16 + 4 * g + rr;  // k-col within tile held by this lane
        float sv = ((mw >> kcl) & 1ull) ? -1e30f : st[kc][rr] * 0.125f;
        s[kc * 4 + rr] = sv;
        mloc = fmaxf(mloc, sv);
      }
    mloc = fmaxf(mloc, __shfl_xor(mloc, 16));
    mloc = fmaxf(mloc, __shfl_xor(mloc, 32));
    float m_new = fmaxf(m_run, mloc);
    float p[16];
    float psum = 0.f;
#pragma unroll
    for (int i = 0; i < 16; ++i) {
      float pv = (s[i] <= -1e29f) ? 0.f : __expf(s[i] - m_new);
      p[i] = pv;
      psum += pv;
    }
    psum += __shfl_xor(psum, 16);
    psum += __shfl_xor(psum, 32);
    float alpha = __expf(m_run - m_new);
    l_run = l_run * alpha + psum;
    m_run = m_new;
    // alpha for accumulator rows 4g+rr lives at lane (4g+rr)
    float a0 = __shfl(alpha, 4 * g + 0);
    float a1 = __shfl(alpha, 4 * g + 1);
    float a2 = __shfl(alpha, 4 * g + 2);
    float a3 = __shfl(alpha, 4 * g + 3);
#pragma unroll
    for (int dvs = 0; dvs < 4; ++dvs) {
      acc[dvs][0] *= a0; acc[dvs][1] *= a1;
      acc[dvs][2] *= a2; acc[dvs][3] *= a3;
    }
    // P A-frags under permuted contraction: phys k=8g+j <-> kcol=(j>>2)*16+4g+(j&3)
    short8 pa0, pa1;
#pragma unroll
    for (int j = 0; j < 8; ++j) { pa0[j] = f2b(p[j]); pa1[j] = f2b(p[8 + j]); }
#pragma unroll
    for (int dvs = 0; dvs < 4; ++dvs) {
      const bf16* Vrow = Vp + (size_t)(dvs * 16 + r) * 2048 + kt * 64;
      short4b v0 = load4(Vrow + 4 * g);
      short4b v1 = load4(Vrow + 16 + 4 * g);
      short4b v2 = load4(Vrow + 32 + 4 * g);
      short4b v3 = load4(Vrow + 48 + 4 * g);
      short8 vb0 = {v0[0], v0[1], v0[2], v0[3], v1[0], v1[1], v1[2], v1[3]};
      short8 vb1 = {v2[0], v2[1], v2[2], v2[3], v3[0], v3[1], v3[2], v3[3]};
      acc[dvs] = __builtin_amdgcn_mfma_f32_16x16x32_bf16(pa0, vb0, acc[dvs], 0, 0, 0);
      acc[dvs] = __builtin_amdgcn_mfma_f32_16x16x32_bf16(pa1, vb1, acc[dvs], 0, 0, 0);
    }
  }
  float l0 = __shfl(l_run, 4 * g + 0);
  float l1 = __shfl(l_run, 4 * g + 1);
  float l2 = __shfl(l_run, 4 * g + 2);
  float l3 = __shfl(l_run, 4 * g + 3);
  float i0 = (l0 > 0.f) ? 1.f / l0 : 0.f;
  float i1 = (l1 > 0.f) ? 1.f / l1 : 0.f;
  float i2 = (l2 > 0.f) ? 1.f / l2 : 0.f;
  float i3 = (l3 > 0.f) ? 1.f / l3 : 0.f;
  // O layout [b*2048+n][h*64+dv]
  bf16* Op = O + ((size_t)b * 2048 + qbase + 4 * g) * 512 + h * 64;
#pragma unroll
  for (int dvs = 0; dvs < 4; ++dvs) {
    Op[0 * 512 + dvs * 16 + r] = __float2bfloat16(acc[dvs][0] * i0);
    Op[1 * 512 + dvs * 16 + r] = __float2bfloat16(acc[dvs][1] * i1);
    Op[2 * 512 + dvs * 16 + r] = __float2bfloat16(acc[dvs][2] * i2);
    Op[3 * 512 + dvs * 16 + r] = __float2bfloat16(acc[dvs][3] * i3);
  }
}

// ---------------- launch ----------------

extern "C" void kernel_launch(void* const* d_in, const int* in_sizes, int n_in,
                              void* d_out, int out_size, void* d_ws, size_t ws_size,
                              hipStream_t stream) {
  const float* q    = (const float*)d_in[0];  // (4,2048,512)
  const int*   mask = (const int*)d_in[1];    // (4,2048,2048)
  const float* Wq   = (const float*)d_in[2];  // (8,512,64)
  const float* Wk   = (const float*)d_in[3];
  const float* Wv   = (const float*)d_in[4];
  const float* Wo   = (const float*)d_in[5];  // (8,64,512)
  float* out = (float*)d_out;

  char* ws = (char*)d_ws;
  const size_t MB1 = 1024 * 1024;
  bf16* Xb  = (bf16*)(ws + 0);          // 8 MB  [8192][512]
  bf16* Qb  = (bf16*)(ws + 8 * MB1);    // 8 MB  [b][h][n][64]
  bf16* Kb  = (bf16*)(ws + 16 * MB1);   // 8 MB  [b][h][n][64]
  bf16* Vtb = (bf16*)(ws + 24 * MB1);   // 8 MB  [b][h*64+dv][n]
  bf16* Ob  = (bf16*)(ws + 32 * MB1);   // 8 MB  [bn][512]
  unsigned long long* Mbits = (unsigned long long*)(ws + 40 * MB1);  // 2 MB
  bf16* Wqt = (bf16*)(ws + 42 * MB1);
  bf16* Wkt = (bf16*)(ws + 42 * MB1 + 1 * 524288);
  bf16* Wvt = (bf16*)(ws + 42 * MB1 + 2 * 524288);
  bf16* Wot = (bf16*)(ws + 42 * MB1 + 3 * 524288);

  k_xconv<<<4096, 256, 0, stream>>>((const float4*)q, (ushort4*)Xb);
  k_maskpack<<<65536, 256, 0, stream>>>(mask, Mbits);
  k_wprep<<<4096, 256, 0, stream>>>(Wq, Wk, Wv, Wo, Wqt, Wkt, Wvt, Wot);
  k_proj_qk<<<dim3(128, 8, 2), 256, 0, stream>>>(Xb, Wqt, Wkt, Qb, Kb);
  k_proj_v<<<dim3(8, 128), 256, 0, stream>>>(Wvt, Xb, Vtb);
  k_attn<<<dim3(32, 32), 256, 0, stream>>>(Qb, Kb, Vtb, Mbits, Ob);
  k_proj_out<<<dim3(128, 8), 256, 0, stream>>>(Ob, Wot, out);
}

// Round 2
// 394.067 us; speedup vs baseline: 1.6363x; 1.6363x over previous
//
#include <hip/hip_runtime.h>
#include <hip/hip_bf16.h>
#include <stdint.h>

using bf16 = __hip_bfloat16;
typedef __attribute__((ext_vector_type(8))) short short8;
typedef __attribute__((ext_vector_type(4))) short short4b;
typedef __attribute__((ext_vector_type(4))) float f32x4;

__device__ __forceinline__ short8 load8(const bf16* p) {
  return *reinterpret_cast<const short8*>(p);
}
__device__ __forceinline__ short4b load4(const bf16* p) {
  return *reinterpret_cast<const short4b*>(p);
}
__device__ __forceinline__ short f2b(float f) {
  return __builtin_bit_cast(short, __float2bfloat16(f));
}
__device__ __forceinline__ void asy16(const bf16* g, bf16* l) {
  __builtin_amdgcn_global_load_lds(
      (const __attribute__((address_space(1))) void*)g,
      (__attribute__((address_space(3))) void*)l, 16, 0, 0);
}

// ---------------- prep kernels ----------------

__global__ void k_xconv(const float4* __restrict__ x, ushort4* __restrict__ xb) {
  int i = blockIdx.x * 256 + threadIdx.x;
  float4 v = x[i];
  ushort4 o;
  o.x = (unsigned short)__builtin_bit_cast(short, __float2bfloat16(v.x));
  o.y = (unsigned short)__builtin_bit_cast(short, __float2bfloat16(v.y));
  o.z = (unsigned short)__builtin_bit_cast(short, __float2bfloat16(v.z));
  o.w = (unsigned short)__builtin_bit_cast(short, __float2bfloat16(v.w));
  xb[i] = o;
}

__global__ void k_maskpack(const int* __restrict__ mask,
                           unsigned long long* __restrict__ bits) {
  int i = blockIdx.x * 256 + threadIdx.x;
  unsigned long long w = __ballot(mask[i] != 0);
  if ((threadIdx.x & 63) == 0) bits[i >> 6] = w;
}

__global__ void k_wprep(const float* __restrict__ Wq, const float* __restrict__ Wk,
                        const float* __restrict__ Wv, const float* __restrict__ Wo,
                        bf16* __restrict__ Wqt, bf16* __restrict__ Wkt,
                        bf16* __restrict__ Wvt, bf16* __restrict__ Wot) {
  int t = blockIdx.x * 256 + threadIdx.x;
  int which = t >> 18, rr = t & 262143;
  if (which < 3) {
    const float* W = (which == 0) ? Wq : ((which == 1) ? Wk : Wv);
    bf16* Wt = (which == 0) ? Wqt : ((which == 1) ? Wkt : Wvt);
    int h = rr >> 15, rem = rr & 32767, dk = rem >> 9, d = rem & 511;
    Wt[rr] = __float2bfloat16(W[(h * 512 + d) * 64 + dk]);
  } else {
    int e = rr >> 9, hv = rr & 511;
    Wot[rr] = __float2bfloat16(Wo[hv * 512 + e]);
  }
}

// ---------------- GEMM core (unchanged this round) ----------------

__device__ __forceinline__ void gemm64(const bf16* __restrict__ A,
                                       const bf16* __restrict__ Bt,
                                       int rowBase, int colBase, f32x4 acc[4]) {
  const int lane = threadIdx.x & 63;
  const int wave = threadIdx.x >> 6;
  const int g = lane >> 4, r = lane & 15;
  const bf16* aP = A + (size_t)(rowBase + r) * 512 + g * 8;
  const bf16* bP = Bt + (size_t)(colBase + wave * 16 + r) * 512 + g * 8;
#pragma unroll 4
  for (int ks = 0; ks < 16; ++ks) {
    short8 bf = load8(bP + ks * 32);
#pragma unroll
    for (int mt = 0; mt < 4; ++mt) {
      short8 af = load8(aP + (size_t)mt * 16 * 512 + ks * 32);
      acc[mt] = __builtin_amdgcn_mfma_f32_16x16x32_bf16(af, bf, acc[mt], 0, 0, 0);
    }
  }
}

__global__ __launch_bounds__(256) void k_proj_qk(const bf16* __restrict__ Xb,
    const bf16* __restrict__ Wqt, const bf16* __restrict__ Wkt,
    bf16* __restrict__ Qo, bf16* __restrict__ Ko) {
  const bf16* Wt = blockIdx.z ? Wkt : Wqt;
  bf16* Out = blockIdx.z ? Ko : Qo;
  int rowBase = blockIdx.x * 64, colBase = blockIdx.y * 64;
  f32x4 acc[4] = {};
  gemm64(Xb, Wt, rowBase, colBase, acc);
  const int lane = threadIdx.x & 63;
  const int wave = threadIdx.x >> 6;
  const int g = lane >> 4, r = lane & 15;
  int col = colBase + wave * 16 + r;
  int h = col >> 6, dk = col & 63;
#pragma unroll
  for (int mt = 0; mt < 4; ++mt)
#pragma unroll
    for (int rr = 0; rr < 4; ++rr) {
      int row = rowBase + mt * 16 + 4 * g + rr;
      int b = row >> 11, n = row & 2047;
      Out[((size_t)(b * 8 + h) * 2048 + n) * 64 + dk] = __float2bfloat16(acc[mt][rr]);
    }
}

__global__ __launch_bounds__(256) void k_proj_v(const bf16* __restrict__ Wvt,
    const bf16* __restrict__ Xb, bf16* __restrict__ Vt) {
  int rowBase = blockIdx.x * 64, colBase = blockIdx.y * 64;
  f32x4 acc[4] = {};
  gemm64(Wvt, Xb, rowBase, colBase, acc);
  const int lane = threadIdx.x & 63;
  const int wave = threadIdx.x >> 6;
  const int g = lane >> 4, r = lane & 15;
  int col = colBase + wave * 16 + r;
  int b = col >> 11, n = col & 2047;
#pragma unroll
  for (int mt = 0; mt < 4; ++mt)
#pragma unroll
    for (int rr = 0; rr < 4; ++rr) {
      int hdv = rowBase + mt * 16 + 4 * g + rr;
      Vt[((size_t)b * 512 + hdv) * 2048 + n] = __float2bfloat16(acc[mt][rr]);
    }
}

__global__ __launch_bounds__(256) void k_proj_out(const bf16* __restrict__ O,
    const bf16* __restrict__ Wot, float* __restrict__ out) {
  int rowBase = blockIdx.x * 64, colBase = blockIdx.y * 64;
  f32x4 acc[4] = {};
  gemm64(O, Wot, rowBase, colBase, acc);
  const int lane = threadIdx.x & 63;
  const int wave = threadIdx.x >> 6;
  const int g = lane >> 4, r = lane & 15;
  int col = colBase + wave * 16 + r;
#pragma unroll
  for (int mt = 0; mt < 4; ++mt)
#pragma unroll
    for (int rr = 0; rr < 4; ++rr) {
      int row = rowBase + mt * 16 + 4 * g + rr;
      out[(size_t)row * 512 + col] = acc[mt][rr];
    }
}

// ---------------- flash attention, LDS double-buffered ----------------
// grid: 1024 linear blocks -> XCD-swizzled (bh, qt). block 128 thr = 2 waves;
// each wave: 32 q rows (2 subtiles of 16). Per kt tile (64 keys):
//  - K[64][64] and Vt[64][64] staged to LDS via global_load_lds (16B), XOR
//    swizzle on 16B granules (g ^ (row&7)) -> conflict-free frag reads.
//  - S^T = K*Q^T (C: row=kcol, col=qrow) -> softmax rows via 2 shfl_xor.
//  - PV with permuted contraction kcol = (j>>2)*16 + 4g + (j&3).
__global__ __launch_bounds__(128) void k_attn(const bf16* __restrict__ Q,
    const bf16* __restrict__ K, const bf16* __restrict__ Vt,
    const unsigned long long* __restrict__ MB, bf16* __restrict__ O) {
  // XCD-aware swizzle: 8 XCDs round-robin by blockIdx; 4 heads per XCD.
  const int blin = blockIdx.x;
  const int j = blin >> 3;
  const int bh = (blin & 7) * 4 + (j >> 5);
  const int qt = j & 31;
  const int b = bh >> 3, h = bh & 7;
  const int tid = threadIdx.x;
  const int lane = tid & 63;
  const int wave = tid >> 6;
  const int g = lane >> 4, r = lane & 15;
  const int rx = r & 7;
  const int qbase = qt * 64 + wave * 32;

  __shared__ __align__(16) bf16 Kl[2][64 * 64];
  __shared__ __align__(16) bf16 Vl[2][64 * 64];

  const bf16* Kp = K + (size_t)bh * 2048 * 64;
  const bf16* Vp = Vt + (size_t)bh * 64 * 2048;

  // Q fragments for both q-subtiles (held in regs whole kernel)
  short8 qf[2][2];
#pragma unroll
  for (int s = 0; s < 2; ++s) {
    const bf16* Qp = Q + ((size_t)bh * 2048 + qbase + s * 16 + r) * 64;
    qf[s][0] = load8(Qp + g * 8);
    qf[s][1] = load8(Qp + 32 + g * 8);
  }
  const unsigned long long* Mp0 = MB + ((size_t)b * 2048 + qbase + r) * 32;
  const unsigned long long* Mp1 = MB + ((size_t)b * 2048 + qbase + 16 + r) * 32;

  float m_run[2] = {-1e30f, -1e30f};
  float l_run[2] = {0.f, 0.f};
  f32x4 acc[2][4] = {};

  // stage tile kt into buffer buf (all 128 threads; lane-contiguous LDS dests,
  // XOR-swizzled global source granules)
  auto stage = [&](int buf, int kt) {
    const bf16* Kg = Kp + kt * 4096;
    const bf16* Vg = Vp + kt * 64;
#pragma unroll
    for (int p = 0; p < 4; ++p) {
      int c = p * 128 + tid;           // 16B chunk 0..511
      int row = c >> 3, gr = c & 7;
      int sg = gr ^ (row & 7);
      asy16(Kg + row * 64 + sg * 8, &Kl[buf][0] + c * 8);
    }
#pragma unroll
    for (int p = 0; p < 4; ++p) {
      int c = p * 128 + tid;
      int row = c >> 3, gr = c & 7;
      int sg = gr ^ (row & 7);
      asy16(Vg + (size_t)row * 2048 + sg * 8, &Vl[buf][0] + c * 8);
    }
  };

  stage(0, 0);
  int buf = 0;

  for (int kt = 0; kt < 32; ++kt) {
    __syncthreads();                 // staged(buf) complete + buf^1 free
    if (kt < 31) stage(buf ^ 1, kt + 1);

    unsigned long long mw0 = Mp0[kt];
    unsigned long long mw1 = Mp1[kt];
    const bf16* kl = &Kl[buf][0];
    const bf16* vl = &Vl[buf][0];

    // S^T MFMAs
    f32x4 st[4][2];
#pragma unroll
    for (int kc = 0; kc < 4; ++kc) {
      const bf16* krow = kl + (kc * 16 + r) * 64;
      short8 kf0 = load8(krow + ((g) ^ rx) * 8);        // half0: granule g
      short8 kf1 = load8(krow + ((4 + g) ^ rx) * 8);    // half1: granule 4+g
      f32x4 z0 = {};
      z0 = __builtin_amdgcn_mfma_f32_16x16x32_bf16(kf0, qf[0][0], z0, 0, 0, 0);
      st[kc][0] = __builtin_amdgcn_mfma_f32_16x16x32_bf16(kf1, qf[0][1], z0, 0, 0, 0);
      f32x4 z1 = {};
      z1 = __builtin_amdgcn_mfma_f32_16x16x32_bf16(kf0, qf[1][0], z1, 0, 0, 0);
      st[kc][1] = __builtin_amdgcn_mfma_f32_16x16x32_bf16(kf1, qf[1][1], z1, 0, 0, 0);
    }

    // softmax per q-subtile
    short8 pa[2][2];
    float a_q[2][4];
#pragma unroll
    for (int s = 0; s < 2; ++s) {
      unsigned long long mw = s ? mw1 : mw0;
      float sc[16];
      float mloc = -1e30f;
#pragma unroll
      for (int kc = 0; kc < 4; ++kc)
#pragma unroll
        for (int rr = 0; rr < 4; ++rr) {
          int kcl = kc * 16 + 4 * g + rr;
          float sv = ((mw >> kcl) & 1ull) ? -1e30f : st[kc][s][rr] * 0.125f;
          sc[kc * 4 + rr] = sv;
          mloc = fmaxf(mloc, sv);
        }
      mloc = fmaxf(mloc, __shfl_xor(mloc, 16));
      mloc = fmaxf(mloc, __shfl_xor(mloc, 32));
      float m_new = fmaxf(m_run[s], mloc);
      float p[16];
      float psum = 0.f;
#pragma unroll
      for (int i = 0; i < 16; ++i) {
        float pv = (sc[i] <= -1e29f) ? 0.f : __expf(sc[i] - m_new);
        p[i] = pv;
        psum += pv;
      }
      psum += __shfl_xor(psum, 16);
      psum += __shfl_xor(psum, 32);
      float alpha = __expf(m_run[s] - m_new);
      l_run[s] = l_run[s] * alpha + psum;
      m_run[s] = m_new;
      a_q[s][0] = __shfl(alpha, 4 * g + 0);
      a_q[s][1] = __shfl(alpha, 4 * g + 1);
      a_q[s][2] = __shfl(alpha, 4 * g + 2);
      a_q[s][3] = __shfl(alpha, 4 * g + 3);
#pragma unroll
      for (int j2 = 0; j2 < 8; ++j2) {
        pa[s][0][j2] = f2b(p[j2]);
        pa[s][1][j2] = f2b(p[8 + j2]);
      }
#pragma unroll
      for (int dvs = 0; dvs < 4; ++dvs) {
        acc[s][dvs][0] *= a_q[s][0];
        acc[s][dvs][1] *= a_q[s][1];
        acc[s][dvs][2] *= a_q[s][2];
        acc[s][dvs][3] *= a_q[s][3];
      }
    }

    // PV MFMAs (V frags shared across the two q-subtiles)
#pragma unroll
    for (int dvs = 0; dvs < 4; ++dvs) {
      const bf16* vrow = vl + (dvs * 16 + r) * 64 + (g & 1) * 4;
      short4b v0 = load4(vrow + (((g >> 1)) ^ rx) * 8);
      short4b v1 = load4(vrow + ((2 + (g >> 1)) ^ rx) * 8);
      short4b v2 = load4(vrow + ((4 + (g >> 1)) ^ rx) * 8);
      short4b v3 = load4(vrow + ((6 + (g >> 1)) ^ rx) * 8);
      short8 vb0 = {v0[0], v0[1], v0[2], v0[3], v1[0], v1[1], v1[2], v1[3]};
      short8 vb1 = {v2[0], v2[1], v2[2], v2[3], v3[0], v3[1], v3[2], v3[3]};
#pragma unroll
      for (int s = 0; s < 2; ++s) {
        acc[s][dvs] = __builtin_amdgcn_mfma_f32_16x16x32_bf16(pa[s][0], vb0, acc[s][dvs], 0, 0, 0);
        acc[s][dvs] = __builtin_amdgcn_mfma_f32_16x16x32_bf16(pa[s][1], vb1, acc[s][dvs], 0, 0, 0);
      }
    }
    buf ^= 1;
  }

  // epilogue
#pragma unroll
  for (int s = 0; s < 2; ++s) {
    float l0 = __shfl(l_run[s], 4 * g + 0);
    float l1 = __shfl(l_run[s], 4 * g + 1);
    float l2 = __shfl(l_run[s], 4 * g + 2);
    float l3 = __shfl(l_run[s], 4 * g + 3);
    float i0 = (l0 > 0.f) ? 1.f / l0 : 0.f;
    float i1 = (l1 > 0.f) ? 1.f / l1 : 0.f;
    float i2 = (l2 > 0.f) ? 1.f / l2 : 0.f;
    float i3 = (l3 > 0.f) ? 1.f / l3 : 0.f;
    bf16* Op = O + ((size_t)b * 2048 + qbase + s * 16 + 4 * g) * 512 + h * 64;
#pragma unroll
    for (int dvs = 0; dvs < 4; ++dvs) {
      Op[0 * 512 + dvs * 16 + r] = __float2bfloat16(acc[s][dvs][0] * i0);
      Op[1 * 512 + dvs * 16 + r] = __float2bfloat16(acc[s][dvs][1] * i1);
      Op[2 * 512 + dvs * 16 + r] = __float2bfloat16(acc[s][dvs][2] * i2);
      Op[3 * 512 + dvs * 16 + r] = __float2bfloat16(acc[s][dvs][3] * i3);
    }
  }
}

// ---------------- launch ----------------

extern "C" void kernel_launch(void* const* d_in, const int* in_sizes, int n_in,
                              void* d_out, int out_size, void* d_ws, size_t ws_size,
                              hipStream_t stream) {
  const float* q    = (const float*)d_in[0];
  const int*   mask = (const int*)d_in[1];
  const float* Wq   = (const float*)d_in[2];
  const float* Wk   = (const float*)d_in[3];
  const float* Wv   = (const float*)d_in[4];
  const float* Wo   = (const float*)d_in[5];
  float* out = (float*)d_out;

  char* ws = (char*)d_ws;
  const size_t MB1 = 1024 * 1024;
  bf16* Xb  = (bf16*)(ws + 0);
  bf16* Qb  = (bf16*)(ws + 8 * MB1);
  bf16* Kb  = (bf16*)(ws + 16 * MB1);
  bf16* Vtb = (bf16*)(ws + 24 * MB1);
  bf16* Ob  = (bf16*)(ws + 32 * MB1);
  unsigned long long* Mbits = (unsigned long long*)(ws + 40 * MB1);
  bf16* Wqt = (bf16*)(ws + 42 * MB1);
  bf16* Wkt = (bf16*)(ws + 42 * MB1 + 1 * 524288);
  bf16* Wvt = (bf16*)(ws + 42 * MB1 + 2 * 524288);
  bf16* Wot = (bf16*)(ws + 42 * MB1 + 3 * 524288);

  k_xconv<<<4096, 256, 0, stream>>>((const float4*)q, (ushort4*)Xb);
  k_maskpack<<<65536, 256, 0, stream>>>(mask, Mbits);
  k_wprep<<<4096, 256, 0, stream>>>(Wq, Wk, Wv, Wo, Wqt, Wkt, Wvt, Wot);
  k_proj_qk<<<dim3(128, 8, 2), 256, 0, stream>>>(Xb, Wqt, Wkt, Qb, Kb);
  k_proj_v<<<dim3(8, 128), 256, 0, stream>>>(Wvt, Xb, Vtb);
  k_attn<<<1024, 128, 0, stream>>>(Qb, Kb, Vtb, Mbits, Ob);
  k_proj_out<<<dim3(128, 8), 256, 0, stream>>>(Ob, Wot, out);
}

// Round 5
// 224.809 us; speedup vs baseline: 2.8682x; 1.7529x over previous
//
#include <hip/hip_runtime.h>
#include <hip/hip_bf16.h>
#include <stdint.h>

using bf16 = __hip_bfloat16;
typedef __attribute__((ext_vector_type(8))) short short8;
typedef __attribute__((ext_vector_type(4))) short short4b;
typedef __attribute__((ext_vector_type(4))) float f32x4;
typedef __attribute__((ext_vector_type(4))) unsigned int u32x4;

#if __has_builtin(__builtin_amdgcn_exp2f)
#define EXP2(x) __builtin_amdgcn_exp2f(x)
#else
#define EXP2(x) exp2f(x)
#endif

__device__ __forceinline__ short8 load8(const bf16* p) {
  return *reinterpret_cast<const short8*>(p);
}
__device__ __forceinline__ short4b load4(const bf16* p) {
  return *reinterpret_cast<const short4b*>(p);
}
__device__ __forceinline__ short f2b(float f) {
  return __builtin_bit_cast(short, __float2bfloat16(f));
}
__device__ __forceinline__ unsigned int pk2(float a, float b) {
  return (unsigned int)(unsigned short)f2b(a) |
         ((unsigned int)(unsigned short)f2b(b) << 16);
}
__device__ __forceinline__ void asy16(const bf16* g, bf16* l) {
  __builtin_amdgcn_global_load_lds(
      (const __attribute__((address_space(1))) void*)g,
      (__attribute__((address_space(3))) void*)l, 16, 0, 0);
}

// ---------------- prep kernels ----------------

__global__ void k_xconv(const float4* __restrict__ x, ushort4* __restrict__ xb) {
  int i = blockIdx.x * 256 + threadIdx.x;
  float4 v = x[i];
  ushort4 o;
  o.x = (unsigned short)__builtin_bit_cast(short, __float2bfloat16(v.x));
  o.y = (unsigned short)__builtin_bit_cast(short, __float2bfloat16(v.y));
  o.z = (unsigned short)__builtin_bit_cast(short, __float2bfloat16(v.z));
  o.w = (unsigned short)__builtin_bit_cast(short, __float2bfloat16(v.w));
  xb[i] = o;
}

// int4-vectorized mask pack: 4 mask ints -> 4 bits, OR-combined across 16 lanes
__global__ void k_maskpack(const int4* __restrict__ m4,
                           unsigned long long* __restrict__ bits) {
  int i = blockIdx.x * 256 + threadIdx.x;  // over 4194304
  int4 v = m4[i];
  unsigned int nib = (unsigned)(v.x != 0) | ((unsigned)(v.y != 0) << 1) |
                     ((unsigned)(v.z != 0) << 2) | ((unsigned)(v.w != 0) << 3);
  unsigned long long w = (unsigned long long)nib << (4 * (threadIdx.x & 15));
  w |= __shfl_xor(w, 1);
  w |= __shfl_xor(w, 2);
  w |= __shfl_xor(w, 4);
  w |= __shfl_xor(w, 8);
  if ((threadIdx.x & 15) == 0) bits[i >> 4] = w;
}

// Wcat[1536][512]: rows 0-511 Wq^T (x 0.125*log2e), 512-1023 Wk^T, 1024-1535 Wv^T.
// Wot[512][512]: Wot[e][h*64+v] = Wo[h][v][e].
__global__ void k_wprep(const float* __restrict__ Wq, const float* __restrict__ Wk,
                        const float* __restrict__ Wv, const float* __restrict__ Wo,
                        bf16* __restrict__ Wcat, bf16* __restrict__ Wot) {
  int t = blockIdx.x * 256 + threadIdx.x;  // over 1048576
  if (t < 786432) {
    int rr = t >> 9, d = t & 511;
    int which = rr >> 9;
    int hdk = rr & 511, h = hdk >> 6, dk = hdk & 63;
    const float* W = (which == 0) ? Wq : ((which == 1) ? Wk : Wv);
    float v = W[(h * 512 + d) * 64 + dk];
    if (which == 0) v *= 0.18033688011112042f;  // 0.125 * log2(e)
    Wcat[t] = __float2bfloat16(v);
  } else {
    int u = t - 786432;
    int e = u >> 9, hv = u & 511;
    Wot[u] = __float2bfloat16(Wo[hv * 512 + e]);
  }
}

// ---------------- 128x128 double-buffered GEMM core ----------------
// C[128x128] = A[M][512] * Bt[N][512]^T, BK=64, 4 waves (wave w: rows
// (w>>1)*64, cols (w&1)*64), LDS tiles [128][64] with 16B-chunk XOR swizzle
// (granule ^ row&7), staged via global_load_lds width=16.
__device__ __forceinline__ void gemm128(const bf16* __restrict__ A,
                                        const bf16* __restrict__ Bt,
                                        bf16* As, bf16* Bs,
                                        int rowBase, int colBase,
                                        f32x4 acc[4][4]) {
  const int tid = threadIdx.x;
  const int lane = tid & 63, w = tid >> 6;
  const int g = lane >> 4, r = lane & 15;

  auto stage = [&](int buf, int s) {
#pragma unroll
    for (int p = 0; p < 4; ++p) {
      int c = p * 256 + tid;
      int row = c >> 3, w8 = c & 7, sg = w8 ^ (row & 7);
      asy16(A + (size_t)(rowBase + row) * 512 + s * 64 + sg * 8,
            As + buf * 8192 + c * 8);
    }
#pragma unroll
    for (int p = 0; p < 4; ++p) {
      int c = p * 256 + tid;
      int row = c >> 3, w8 = c & 7, sg = w8 ^ (row & 7);
      asy16(Bt + (size_t)(colBase + row) * 512 + s * 64 + sg * 8,
            Bs + buf * 8192 + c * 8);
    }
  };

  stage(0, 0);
  int buf = 0;
  const int rbl = (w >> 1) * 64, cbl = (w & 1) * 64;
  for (int s = 0; s < 8; ++s) {
    __syncthreads();
    if (s < 7) stage(buf ^ 1, s + 1);
    const bf16* a0 = As + buf * 8192;
    const bf16* b0 = Bs + buf * 8192;
#pragma unroll
    for (int kk = 0; kk < 2; ++kk) {
      short8 af[4], bfr[4];
#pragma unroll
      for (int mt = 0; mt < 4; ++mt) {
        int row = rbl + mt * 16 + r;
        af[mt] = load8(a0 + (row * 8 + ((kk * 4 + g) ^ (row & 7))) * 8);
      }
#pragma unroll
      for (int nt = 0; nt < 4; ++nt) {
        int col = cbl + nt * 16 + r;
        bfr[nt] = load8(b0 + (col * 8 + ((kk * 4 + g) ^ (col & 7))) * 8);
      }
#pragma unroll
      for (int mt = 0; mt < 4; ++mt)
#pragma unroll
        for (int nt = 0; nt < 4; ++nt)
          acc[mt][nt] = __builtin_amdgcn_mfma_f32_16x16x32_bf16(
              af[mt], bfr[nt], acc[mt][nt], 0, 0, 0);
    }
    buf ^= 1;
  }
}

// Fused QKV projection: A=Xb[8192][512], Bt=Wcat[1536][512].
// cols 0-511 -> Qb [bh][n][dk]; 512-1023 -> Kb; 1024-1535 -> Vt [b][hdv][n].
__global__ __launch_bounds__(256, 2) void k_proj_qkv(
    const bf16* __restrict__ Xb, const bf16* __restrict__ Wcat,
    bf16* __restrict__ Qb, bf16* __restrict__ Kb, bf16* __restrict__ Vt) {
  __shared__ __align__(16) bf16 As[2 * 8192];
  __shared__ __align__(16) bf16 Bs[2 * 8192];
  int rowBase = blockIdx.x * 128, colBase = blockIdx.y * 128;
  f32x4 acc[4][4] = {};
  gemm128(Xb, Wcat, As, Bs, rowBase, colBase, acc);
  const int lane = threadIdx.x & 63, w = threadIdx.x >> 6;
  const int g = lane >> 4, r = lane & 15;
#pragma unroll
  for (int mt = 0; mt < 4; ++mt) {
    int row0 = rowBase + (w >> 1) * 64 + mt * 16 + 4 * g;
    int b = row0 >> 11, n0 = row0 & 2047;
#pragma unroll
    for (int nt = 0; nt < 4; ++nt) {
      int col = colBase + (w & 1) * 64 + nt * 16 + r;
      if (col < 1024) {
        bf16* dst = (col < 512) ? Qb : Kb;
        int hh = (col >> 6) & 7, dk = col & 63;
        bf16* p0 = dst + ((size_t)(b * 8 + hh) * 2048 + n0) * 64 + dk;
#pragma unroll
        for (int rr = 0; rr < 4; ++rr)
          p0[rr * 64] = __float2bfloat16(acc[mt][nt][rr]);
      } else {
        int hdv = col - 1024;
        short4b pkv;
#pragma unroll
        for (int rr = 0; rr < 4; ++rr) pkv[rr] = f2b(acc[mt][nt][rr]);
        *reinterpret_cast<short4b*>(Vt + ((size_t)b * 512 + hdv) * 2048 + n0) = pkv;
      }
    }
  }
}

// Output projection: A=Ob[8192][512], Bt=Wot[512][512], fp32 out.
__global__ __launch_bounds__(256, 2) void k_proj_out(
    const bf16* __restrict__ O, const bf16* __restrict__ Wot,
    float* __restrict__ out) {
  __shared__ __align__(16) bf16 As[2 * 8192];
  __shared__ __align__(16) bf16 Bs[2 * 8192];
  int rowBase = blockIdx.x * 128, colBase = blockIdx.y * 128;
  f32x4 acc[4][4] = {};
  gemm128(O, Wot, As, Bs, rowBase, colBase, acc);
  const int lane = threadIdx.x & 63, w = threadIdx.x >> 6;
  const int g = lane >> 4, r = lane & 15;
#pragma unroll
  for (int mt = 0; mt < 4; ++mt) {
    int row0 = rowBase + (w >> 1) * 64 + mt * 16 + 4 * g;
#pragma unroll
    for (int nt = 0; nt < 4; ++nt) {
      int col = colBase + (w & 1) * 64 + nt * 16 + r;
#pragma unroll
      for (int rr = 0; rr < 4; ++rr)
        out[(size_t)(row0 + rr) * 512 + col] = acc[mt][nt][rr];
    }
  }
}

// ---------------- flash attention, max-free exp2 softmax ----------------
// grid 512 (XCD-swizzled bh x 16 qt-tiles of 128 rows), 256 thr = 4 waves,
// 32 q-rows per wave. Scores pre-scaled (0.125*log2e folded into Wq) so
// p = exp2(st); mask -> p=0; l accumulated per-lane, reduced once at end.
__global__ __launch_bounds__(256, 2) void k_attn(const bf16* __restrict__ Q,
    const bf16* __restrict__ K, const bf16* __restrict__ Vt,
    const unsigned long long* __restrict__ MB, bf16* __restrict__ O) {
  const int blin = blockIdx.x;
  const int j = blin >> 3;
  const int bh = (blin & 7) * 4 + (j >> 4);
  const int qt = j & 15;
  const int b = bh >> 3, h = bh & 7;
  const int tid = threadIdx.x;
  const int lane = tid & 63;
  const int wave = tid >> 6;
  const int g = lane >> 4, r = lane & 15;
  const int rx = r & 7;
  const int qbase = qt * 128 + wave * 32;

  __shared__ __align__(16) bf16 Kl[2][64 * 64];
  __shared__ __align__(16) bf16 Vl[2][64 * 64];

  const bf16* Kp = K + (size_t)bh * 2048 * 64;
  const bf16* Vp = Vt + (size_t)bh * 64 * 2048;

  short8 qf[2][2];
#pragma unroll
  for (int s = 0; s < 2; ++s) {
    const bf16* Qp = Q + ((size_t)bh * 2048 + qbase + s * 16 + r) * 64;
    qf[s][0] = load8(Qp + g * 8);
    qf[s][1] = load8(Qp + 32 + g * 8);
  }
  const unsigned long long* Mp0 = MB + ((size_t)b * 2048 + qbase + r) * 32;
  const unsigned long long* Mp1 = MB + ((size_t)b * 2048 + qbase + 16 + r) * 32;

  float l_part[2] = {0.f, 0.f};
  f32x4 acc[2][4] = {};

  auto stage = [&](int buf, int kt) {
    const bf16* Kg = Kp + kt * 4096;
    const bf16* Vg = Vp + kt * 64;
#pragma unroll
    for (int p = 0; p < 2; ++p) {
      int c = p * 256 + tid;
      int row = c >> 3, gr = c & 7, sg = gr ^ (row & 7);
      asy16(Kg + row * 64 + sg * 8, &Kl[buf][0] + c * 8);
    }
#pragma unroll
    for (int p = 0; p < 2; ++p) {
      int c = p * 256 + tid;
      int row = c >> 3, gr = c & 7, sg = gr ^ (row & 7);
      asy16(Vg + (size_t)row * 2048 + sg * 8, &Vl[buf][0] + c * 8);
    }
  };

  stage(0, 0);
  int buf = 0;

  for (int kt = 0; kt < 32; ++kt) {
    __syncthreads();
    if (kt < 31) stage(buf ^ 1, kt + 1);

    unsigned long long mw0 = Mp0[kt];
    unsigned long long mw1 = Mp1[kt];
    const bf16* kl = &Kl[buf][0];
    const bf16* vl = &Vl[buf][0];

    // S^T = K * Q^T
    f32x4 st[4][2];
#pragma unroll
    for (int kc = 0; kc < 4; ++kc) {
      const bf16* krow = kl + (kc * 16 + r) * 64;
      short8 kf0 = load8(krow + ((g) ^ rx) * 8);
      short8 kf1 = load8(krow + ((4 + g) ^ rx) * 8);
      f32x4 z0 = {};
      z0 = __builtin_amdgcn_mfma_f32_16x16x32_bf16(kf0, qf[0][0], z0, 0, 0, 0);
      st[kc][0] = __builtin_amdgcn_mfma_f32_16x16x32_bf16(kf1, qf[0][1], z0, 0, 0, 0);
      f32x4 z1 = {};
      z1 = __builtin_amdgcn_mfma_f32_16x16x32_bf16(kf0, qf[1][0], z1, 0, 0, 0);
      st[kc][1] = __builtin_amdgcn_mfma_f32_16x16x32_bf16(kf1, qf[1][1], z1, 0, 0, 0);
    }

    // max-free softmax per q-subtile
    short8 pa[2][2];
#pragma unroll
    for (int s = 0; s < 2; ++s) {
      unsigned long long mw = s ? mw1 : mw0;
      unsigned ml = (unsigned)mw >> (4 * g);
      unsigned mh = (unsigned)(mw >> 32) >> (4 * g);
      float p[16];
#pragma unroll
      for (int kc = 0; kc < 4; ++kc)
#pragma unroll
        for (int rr = 0; rr < 4; ++rr) {
          float e = EXP2(st[kc][s][rr]);
          unsigned wsel = (kc & 2) ? mh : ml;
          bool bad = (wsel >> (((kc & 1) << 4) + rr)) & 1u;
          p[kc * 4 + rr] = bad ? 0.f : e;
        }
      // pairwise-tree sum into per-lane partial
      float s0 = (p[0] + p[1]) + (p[2] + p[3]);
      float s1 = (p[4] + p[5]) + (p[6] + p[7]);
      float s2 = (p[8] + p[9]) + (p[10] + p[11]);
      float s3 = (p[12] + p[13]) + (p[14] + p[15]);
      l_part[s] += (s0 + s1) + (s2 + s3);
      u32x4 q0, q1;
#pragma unroll
      for (int i2 = 0; i2 < 4; ++i2) {
        q0[i2] = pk2(p[2 * i2], p[2 * i2 + 1]);
        q1[i2] = pk2(p[8 + 2 * i2], p[8 + 2 * i2 + 1]);
      }
      pa[s][0] = __builtin_bit_cast(short8, q0);
      pa[s][1] = __builtin_bit_cast(short8, q1);
    }

    // PV (V frags shared across the two q-subtiles); no rescale (max-free)
#pragma unroll
    for (int dvs = 0; dvs < 4; ++dvs) {
      const bf16* vrow = vl + (dvs * 16 + r) * 64 + (g & 1) * 4;
      short4b v0 = load4(vrow + (((g >> 1)) ^ rx) * 8);
      short4b v1 = load4(vrow + ((2 + (g >> 1)) ^ rx) * 8);
      short4b v2 = load4(vrow + ((4 + (g >> 1)) ^ rx) * 8);
      short4b v3 = load4(vrow + ((6 + (g >> 1)) ^ rx) * 8);
      short8 vb0 = {v0[0], v0[1], v0[2], v0[3], v1[0], v1[1], v1[2], v1[3]};
      short8 vb1 = {v2[0], v2[1], v2[2], v2[3], v3[0], v3[1], v3[2], v3[3]};
#pragma unroll
      for (int s = 0; s < 2; ++s) {
        acc[s][dvs] = __builtin_amdgcn_mfma_f32_16x16x32_bf16(pa[s][0], vb0, acc[s][dvs], 0, 0, 0);
        acc[s][dvs] = __builtin_amdgcn_mfma_f32_16x16x32_bf16(pa[s][1], vb1, acc[s][dvs], 0, 0, 0);
      }
    }
    buf ^= 1;
  }

  // epilogue: reduce l across g-groups once, then normalize + store
#pragma unroll
  for (int s = 0; s < 2; ++s) {
    float l = l_part[s];
    l += __shfl_xor(l, 16);
    l += __shfl_xor(l, 32);
    float l0 = __shfl(l, 4 * g + 0);
    float l1 = __shfl(l, 4 * g + 1);
    float l2 = __shfl(l, 4 * g + 2);
    float l3 = __shfl(l, 4 * g + 3);
    float i0 = (l0 > 0.f) ? 1.f / l0 : 0.f;
    float i1 = (l1 > 0.f) ? 1.f / l1 : 0.f;
    float i2 = (l2 > 0.f) ? 1.f / l2 : 0.f;
    float i3 = (l3 > 0.f) ? 1.f / l3 : 0.f;
    bf16* Op = O + ((size_t)b * 2048 + qbase + s * 16 + 4 * g) * 512 + h * 64;
#pragma unroll
    for (int dvs = 0; dvs < 4; ++dvs) {
      Op[0 * 512 + dvs * 16 + r] = __float2bfloat16(acc[s][dvs][0] * i0);
      Op[1 * 512 + dvs * 16 + r] = __float2bfloat16(acc[s][dvs][1] * i1);
      Op[2 * 512 + dvs * 16 + r] = __float2bfloat16(acc[s][dvs][2] * i2);
      Op[3 * 512 + dvs * 16 + r] = __float2bfloat16(acc[s][dvs][3] * i3);
    }
  }
}

// ---------------- launch ----------------

extern "C" void kernel_launch(void* const* d_in, const int* in_sizes, int n_in,
                              void* d_out, int out_size, void* d_ws, size_t ws_size,
                              hipStream_t stream) {
  const float* q    = (const float*)d_in[0];
  const int*   mask = (const int*)d_in[1];
  const float* Wq   = (const float*)d_in[2];
  const float* Wk   = (const float*)d_in[3];
  const float* Wv   = (const float*)d_in[4];
  const float* Wo   = (const float*)d_in[5];
  float* out = (float*)d_out;

  char* ws = (char*)d_ws;
  const size_t MB1 = 1024 * 1024;
  bf16* Xb   = (bf16*)(ws + 0);          // 8 MB [8192][512]
  bf16* Qb   = (bf16*)(ws + 8 * MB1);    // 8 MB [bh][n][64]
  bf16* Kb   = (bf16*)(ws + 16 * MB1);   // 8 MB [bh][n][64]
  bf16* Vtb  = (bf16*)(ws + 24 * MB1);   // 8 MB [b][hdv][n]
  bf16* Ob   = (bf16*)(ws + 32 * MB1);   // 8 MB [bn][512]
  unsigned long long* Mbits = (unsigned long long*)(ws + 40 * MB1);  // 2 MB
  bf16* Wcat = (bf16*)(ws + 42 * MB1);   // 1.5 MB [1536][512]
  bf16* Wot  = (bf16*)(ws + 42 * MB1 + 1536 * 512 * 2);  // 0.5 MB [512][512]

  k_xconv<<<4096, 256, 0, stream>>>((const float4*)q, (ushort4*)Xb);
  k_maskpack<<<16384, 256, 0, stream>>>((const int4*)mask, Mbits);
  k_wprep<<<4096, 256, 0, stream>>>(Wq, Wk, Wv, Wo, Wcat, Wot);
  k_proj_qkv<<<dim3(64, 12), 256, 0, stream>>>(Xb, Wcat, Qb, Kb, Vtb);
  k_attn<<<512, 256, 0, stream>>>(Qb, Kb, Vtb, Mbits, Ob);
  k_proj_out<<<dim3(64, 4), 256, 0, stream>>>(Ob, Wot, out);
}

// Round 6
// 223.715 us; speedup vs baseline: 2.8822x; 1.0049x over previous
//
#include <hip/hip_runtime.h>
#include <hip/hip_bf16.h>
#include <stdint.h>

using bf16 = __hip_bfloat16;
typedef __attribute__((ext_vector_type(8))) short short8;
typedef __attribute__((ext_vector_type(4))) short short4b;
typedef __attribute__((ext_vector_type(4))) float f32x4;
typedef __attribute__((ext_vector_type(4))) unsigned int u32x4;

#if __has_builtin(__builtin_amdgcn_exp2f)
#define EXP2(x) __builtin_amdgcn_exp2f(x)
#else
#define EXP2(x) exp2f(x)
#endif

__device__ __forceinline__ short8 load8(const bf16* p) {
  return *reinterpret_cast<const short8*>(p);
}
__device__ __forceinline__ short4b load4(const bf16* p) {
  return *reinterpret_cast<const short4b*>(p);
}
__device__ __forceinline__ short f2b(float f) {
  return __builtin_bit_cast(short, __float2bfloat16(f));
}
__device__ __forceinline__ unsigned int pk2(float a, float b) {
  return (unsigned int)(unsigned short)f2b(a) |
         ((unsigned int)(unsigned short)f2b(b) << 16);
}
__device__ __forceinline__ void asy16(const bf16* g, bf16* l) {
  __builtin_amdgcn_global_load_lds(
      (const __attribute__((address_space(1))) void*)g,
      (__attribute__((address_space(3))) void*)l, 16, 0, 0);
}

// ---------------- fused prep kernel ----------------
// blocks [0,4096): x f32->bf16 ; [4096,8192): weight transpose/cat ;
// [8192,24576): mask bit-pack (int4 per thread).
__global__ void k_prep(const float4* __restrict__ x, ushort4* __restrict__ xb,
                       const float* __restrict__ Wq, const float* __restrict__ Wk,
                       const float* __restrict__ Wv, const float* __restrict__ Wo,
                       bf16* __restrict__ Wcat, bf16* __restrict__ Wot,
                       const int4* __restrict__ m4,
                       unsigned long long* __restrict__ bits) {
  int blk = blockIdx.x;
  if (blk < 4096) {
    int i = blk * 256 + threadIdx.x;
    float4 v = x[i];
    ushort4 o;
    o.x = (unsigned short)f2b(v.x);
    o.y = (unsigned short)f2b(v.y);
    o.z = (unsigned short)f2b(v.z);
    o.w = (unsigned short)f2b(v.w);
    xb[i] = o;
  } else if (blk < 8192) {
    int t = (blk - 4096) * 256 + threadIdx.x;  // over 1048576
    if (t < 786432) {
      int rr = t >> 9, d = t & 511;
      int which = rr >> 9;
      int hdk = rr & 511, h = hdk >> 6, dk = hdk & 63;
      const float* W = (which == 0) ? Wq : ((which == 1) ? Wk : Wv);
      float v = W[(h * 512 + d) * 64 + dk];
      if (which == 0) v *= 0.18033688011112042f;  // 0.125 * log2(e)
      Wcat[t] = __float2bfloat16(v);
    } else {
      int u = t - 786432;
      int e = u >> 9, hv = u & 511;
      Wot[u] = __float2bfloat16(Wo[hv * 512 + e]);
    }
  } else {
    int i = (blk - 8192) * 256 + threadIdx.x;  // over 4194304
    int4 v = m4[i];
    unsigned int nib = (unsigned)(v.x != 0) | ((unsigned)(v.y != 0) << 1) |
                       ((unsigned)(v.z != 0) << 2) | ((unsigned)(v.w != 0) << 3);
    unsigned long long w = (unsigned long long)nib << (4 * (threadIdx.x & 15));
    w |= __shfl_xor(w, 1);
    w |= __shfl_xor(w, 2);
    w |= __shfl_xor(w, 4);
    w |= __shfl_xor(w, 8);
    if ((threadIdx.x & 15) == 0) bits[i >> 4] = w;
  }
}

// ---------------- 128x128 double-buffered GEMM core ----------------
__device__ __forceinline__ void gemm128(const bf16* __restrict__ A,
                                        const bf16* __restrict__ Bt,
                                        bf16* As, bf16* Bs,
                                        int rowBase, int colBase,
                                        f32x4 acc[4][4]) {
  const int tid = threadIdx.x;
  const int lane = tid & 63, w = tid >> 6;
  const int g = lane >> 4, r = lane & 15;

  auto stage = [&](int buf, int s) {
#pragma unroll
    for (int p = 0; p < 4; ++p) {
      int c = p * 256 + tid;
      int row = c >> 3, w8 = c & 7, sg = w8 ^ (row & 7);
      asy16(A + (size_t)(rowBase + row) * 512 + s * 64 + sg * 8,
            As + buf * 8192 + c * 8);
    }
#pragma unroll
    for (int p = 0; p < 4; ++p) {
      int c = p * 256 + tid;
      int row = c >> 3, w8 = c & 7, sg = w8 ^ (row & 7);
      asy16(Bt + (size_t)(colBase + row) * 512 + s * 64 + sg * 8,
            Bs + buf * 8192 + c * 8);
    }
  };

  stage(0, 0);
  int buf = 0;
  const int rbl = (w >> 1) * 64, cbl = (w & 1) * 64;
  for (int s = 0; s < 8; ++s) {
    __syncthreads();
    if (s < 7) stage(buf ^ 1, s + 1);
    const bf16* a0 = As + buf * 8192;
    const bf16* b0 = Bs + buf * 8192;
#pragma unroll
    for (int kk = 0; kk < 2; ++kk) {
      short8 af[4], bfr[4];
#pragma unroll
      for (int mt = 0; mt < 4; ++mt) {
        int row = rbl + mt * 16 + r;
        af[mt] = load8(a0 + (row * 8 + ((kk * 4 + g) ^ (row & 7))) * 8);
      }
#pragma unroll
      for (int nt = 0; nt < 4; ++nt) {
        int col = cbl + nt * 16 + r;
        bfr[nt] = load8(b0 + (col * 8 + ((kk * 4 + g) ^ (col & 7))) * 8);
      }
#pragma unroll
      for (int mt = 0; mt < 4; ++mt)
#pragma unroll
        for (int nt = 0; nt < 4; ++nt)
          acc[mt][nt] = __builtin_amdgcn_mfma_f32_16x16x32_bf16(
              af[mt], bfr[nt], acc[mt][nt], 0, 0, 0);
    }
    buf ^= 1;
  }
}

// Fused QKV projection: A=Xb[8192][512], Bt=Wcat[1536][512].
__global__ __launch_bounds__(256, 2) void k_proj_qkv(
    const bf16* __restrict__ Xb, const bf16* __restrict__ Wcat,
    bf16* __restrict__ Qb, bf16* __restrict__ Kb, bf16* __restrict__ Vt) {
  __shared__ __align__(16) bf16 As[2 * 8192];
  __shared__ __align__(16) bf16 Bs[2 * 8192];
  int rowBase = blockIdx.x * 128, colBase = blockIdx.y * 128;
  f32x4 acc[4][4] = {};
  gemm128(Xb, Wcat, As, Bs, rowBase, colBase, acc);
  const int lane = threadIdx.x & 63, w = threadIdx.x >> 6;
  const int g = lane >> 4, r = lane & 15;
#pragma unroll
  for (int mt = 0; mt < 4; ++mt) {
    int row0 = rowBase + (w >> 1) * 64 + mt * 16 + 4 * g;
    int b = row0 >> 11, n0 = row0 & 2047;
#pragma unroll
    for (int nt = 0; nt < 4; ++nt) {
      int col = colBase + (w & 1) * 64 + nt * 16 + r;
      if (col < 1024) {
        bf16* dst = (col < 512) ? Qb : Kb;
        int hh = (col >> 6) & 7, dk = col & 63;
        bf16* p0 = dst + ((size_t)(b * 8 + hh) * 2048 + n0) * 64 + dk;
#pragma unroll
        for (int rr = 0; rr < 4; ++rr)
          p0[rr * 64] = __float2bfloat16(acc[mt][nt][rr]);
      } else {
        int hdv = col - 1024;
        short4b pkv;
#pragma unroll
        for (int rr = 0; rr < 4; ++rr) pkv[rr] = f2b(acc[mt][nt][rr]);
        *reinterpret_cast<short4b*>(Vt + ((size_t)b * 512 + hdv) * 2048 + n0) = pkv;
      }
    }
  }
}

// Output projection: A=Ob[8192][512], Bt=Wot[512][512], fp32 out.
__global__ __launch_bounds__(256, 2) void k_proj_out(
    const bf16* __restrict__ O, const bf16* __restrict__ Wot,
    float* __restrict__ out) {
  __shared__ __align__(16) bf16 As[2 * 8192];
  __shared__ __align__(16) bf16 Bs[2 * 8192];
  int rowBase = blockIdx.x * 128, colBase = blockIdx.y * 128;
  f32x4 acc[4][4] = {};
  gemm128(O, Wot, As, Bs, rowBase, colBase, acc);
  const int lane = threadIdx.x & 63, w = threadIdx.x >> 6;
  const int g = lane >> 4, r = lane & 15;
#pragma unroll
  for (int mt = 0; mt < 4; ++mt) {
    int row0 = rowBase + (w >> 1) * 64 + mt * 16 + 4 * g;
#pragma unroll
    for (int nt = 0; nt < 4; ++nt) {
      int col = colBase + (w & 1) * 64 + nt * 16 + r;
#pragma unroll
      for (int rr = 0; rr < 4; ++rr)
        out[(size_t)(row0 + rr) * 512 + col] = acc[mt][nt][rr];
    }
  }
}

// ---------------- flash attention ----------------
// grid 1024 (XCD-swizzled bh x 32 qt-tiles of 64 rows), 256 thr = 4 waves,
// 16 q-rows per wave. Max-free exp2 softmax (scale folded into Wq).
// l computed via MFMA row-sum against ones (C rows = 4g+rr, same layout as
// the O accumulator -> shuffle-free epilogue).
__global__ __launch_bounds__(256, 4) void k_attn(const bf16* __restrict__ Q,
    const bf16* __restrict__ K, const bf16* __restrict__ Vt,
    const unsigned long long* __restrict__ MB, bf16* __restrict__ O) {
  const int blin = blockIdx.x;
  const int j = blin >> 3;
  const int bh = (blin & 7) * 4 + (j >> 5);
  const int qt = j & 31;
  const int b = bh >> 3, h = bh & 7;
  const int tid = threadIdx.x;
  const int lane = tid & 63;
  const int wave = tid >> 6;
  const int g = lane >> 4, r = lane & 15;
  const int rx = r & 7;
  const int qbase = qt * 64 + wave * 16;

  __shared__ __align__(16) bf16 Kl[2][64 * 64];
  __shared__ __align__(16) bf16 Vl[2][64 * 64];

  const bf16* Kp = K + (size_t)bh * 2048 * 64;
  const bf16* Vp = Vt + (size_t)bh * 64 * 2048;

  const bf16* Qp = Q + ((size_t)bh * 2048 + qbase + r) * 64;
  short8 qf0 = load8(Qp + g * 8);
  short8 qf1 = load8(Qp + 32 + g * 8);
  const unsigned long long* Mp = MB + ((size_t)b * 2048 + qbase + r) * 32;

  short8 ones;
#pragma unroll
  for (int i = 0; i < 8; ++i) ones[i] = (short)0x3F80;  // bf16 1.0

  f32x4 acc[4] = {};
  f32x4 acc_l = {};

  auto stage = [&](int buf, int kt) {
    const bf16* Kg = Kp + kt * 4096;
    const bf16* Vg = Vp + kt * 64;
#pragma unroll
    for (int p = 0; p < 2; ++p) {
      int c = p * 256 + tid;
      int row = c >> 3, gr = c & 7, sg = gr ^ (row & 7);
      asy16(Kg + row * 64 + sg * 8, &Kl[buf][0] + c * 8);
    }
#pragma unroll
    for (int p = 0; p < 2; ++p) {
      int c = p * 256 + tid;
      int row = c >> 3, gr = c & 7, sg = gr ^ (row & 7);
      asy16(Vg + (size_t)row * 2048 + sg * 8, &Vl[buf][0] + c * 8);
    }
  };

  stage(0, 0);
  int buf = 0;

  for (int kt = 0; kt < 32; ++kt) {
    __syncthreads();
    if (kt < 31) stage(buf ^ 1, kt + 1);

    unsigned long long mw = Mp[kt];
    const bf16* kl = &Kl[buf][0];
    const bf16* vl = &Vl[buf][0];

    // S^T = K * Q^T  (C: row=kcol at 4g+rr, col=qrow at r)
    f32x4 st[4];
#pragma unroll
    for (int kc = 0; kc < 4; ++kc) {
      const bf16* krow = kl + (kc * 16 + r) * 64;
      short8 kf0 = load8(krow + ((g) ^ rx) * 8);
      short8 kf1 = load8(krow + ((4 + g) ^ rx) * 8);
      f32x4 z = {};
      z = __builtin_amdgcn_mfma_f32_16x16x32_bf16(kf0, qf0, z, 0, 0, 0);
      st[kc] = __builtin_amdgcn_mfma_f32_16x16x32_bf16(kf1, qf1, z, 0, 0, 0);
    }

    // max-free softmax: p = exp2(st) masked to 0
    unsigned ml = (unsigned)mw >> (4 * g);
    unsigned mh = (unsigned)(mw >> 32) >> (4 * g);
    float p[16];
#pragma unroll
    for (int kc = 0; kc < 4; ++kc)
#pragma unroll
      for (int rr = 0; rr < 4; ++rr) {
        float e = EXP2(st[kc][rr]);
        unsigned wsel = (kc & 2) ? mh : ml;
        bool bad = (wsel >> (((kc & 1) << 4) + rr)) & 1u;
        p[kc * 4 + rr] = bad ? 0.f : e;
      }
    u32x4 q0, q1;
#pragma unroll
    for (int i2 = 0; i2 < 4; ++i2) {
      q0[i2] = pk2(p[2 * i2], p[2 * i2 + 1]);
      q1[i2] = pk2(p[8 + 2 * i2], p[8 + 2 * i2 + 1]);
    }
    short8 pa0 = __builtin_bit_cast(short8, q0);
    short8 pa1 = __builtin_bit_cast(short8, q1);

    // l row-sums on the matrix pipe (rows 4g+rr match acc layout)
    acc_l = __builtin_amdgcn_mfma_f32_16x16x32_bf16(pa0, ones, acc_l, 0, 0, 0);
    acc_l = __builtin_amdgcn_mfma_f32_16x16x32_bf16(pa1, ones, acc_l, 0, 0, 0);

    // PV with permuted contraction
#pragma unroll
    for (int dvs = 0; dvs < 4; ++dvs) {
      const bf16* vrow = vl + (dvs * 16 + r) * 64 + (g & 1) * 4;
      short4b v0 = load4(vrow + (((g >> 1)) ^ rx) * 8);
      short4b v1 = load4(vrow + ((2 + (g >> 1)) ^ rx) * 8);
      short4b v2 = load4(vrow + ((4 + (g >> 1)) ^ rx) * 8);
      short4b v3 = load4(vrow + ((6 + (g >> 1)) ^ rx) * 8);
      short8 vb0 = {v0[0], v0[1], v0[2], v0[3], v1[0], v1[1], v1[2], v1[3]};
      short8 vb1 = {v2[0], v2[1], v2[2], v2[3], v3[0], v3[1], v3[2], v3[3]};
      acc[dvs] = __builtin_amdgcn_mfma_f32_16x16x32_bf16(pa0, vb0, acc[dvs], 0, 0, 0);
      acc[dvs] = __builtin_amdgcn_mfma_f32_16x16x32_bf16(pa1, vb1, acc[dvs], 0, 0, 0);
    }
    buf ^= 1;
  }

  // shuffle-free epilogue
  float inv[4];
#pragma unroll
  for (int rr = 0; rr < 4; ++rr)
    inv[rr] = (acc_l[rr] > 0.f) ? 1.f / acc_l[rr] : 0.f;
  bf16* Op = O + ((size_t)b * 2048 + qbase + 4 * g) * 512 + h * 64;
#pragma unroll
  for (int dvs = 0; dvs < 4; ++dvs)
#pragma unroll
    for (int rr = 0; rr < 4; ++rr)
      Op[rr * 512 + dvs * 16 + r] = __float2bfloat16(acc[dvs][rr] * inv[rr]);
}

// ---------------- launch ----------------

extern "C" void kernel_launch(void* const* d_in, const int* in_sizes, int n_in,
                              void* d_out, int out_size, void* d_ws, size_t ws_size,
                              hipStream_t stream) {
  const float* q    = (const float*)d_in[0];
  const int*   mask = (const int*)d_in[1];
  const float* Wq   = (const float*)d_in[2];
  const float* Wk   = (const float*)d_in[3];
  const float* Wv   = (const float*)d_in[4];
  const float* Wo   = (const float*)d_in[5];
  float* out = (float*)d_out;

  char* ws = (char*)d_ws;
  const size_t MB1 = 1024 * 1024;
  bf16* Xb   = (bf16*)(ws + 0);          // 8 MB [8192][512]
  bf16* Qb   = (bf16*)(ws + 8 * MB1);    // 8 MB [bh][n][64]
  bf16* Kb   = (bf16*)(ws + 16 * MB1);   // 8 MB [bh][n][64]
  bf16* Vtb  = (bf16*)(ws + 24 * MB1);   // 8 MB [b][hdv][n]
  bf16* Ob   = (bf16*)(ws + 32 * MB1);   // 8 MB [bn][512]
  unsigned long long* Mbits = (unsigned long long*)(ws + 40 * MB1);  // 2 MB
  bf16* Wcat = (bf16*)(ws + 42 * MB1);   // 1.5 MB [1536][512]
  bf16* Wot  = (bf16*)(ws + 42 * MB1 + 1536 * 512 * 2);  // 0.5 MB [512][512]

  k_prep<<<24576, 256, 0, stream>>>((const float4*)q, (ushort4*)Xb,
                                    Wq, Wk, Wv, Wo, Wcat, Wot,
                                    (const int4*)mask, Mbits);
  k_proj_qkv<<<dim3(64, 12), 256, 0, stream>>>(Xb, Wcat, Qb, Kb, Vtb);
  k_attn<<<1024, 256, 0, stream>>>(Qb, Kb, Vtb, Mbits, Ob);
  k_proj_out<<<dim3(64, 4), 256, 0, stream>>>(Ob, Wot, out);
}

// Round 7
// 216.697 us; speedup vs baseline: 2.9756x; 1.0324x over previous
//
#include <hip/hip_runtime.h>
#include <hip/hip_bf16.h>
#include <stdint.h>

using bf16 = __hip_bfloat16;
typedef __attribute__((ext_vector_type(8))) short short8;
typedef __attribute__((ext_vector_type(4))) short short4b;
typedef __attribute__((ext_vector_type(4))) float f32x4;
typedef __attribute__((ext_vector_type(4))) unsigned int u32x4;

#if __has_builtin(__builtin_amdgcn_exp2f)
#define EXP2(x) __builtin_amdgcn_exp2f(x)
#else
#define EXP2(x) exp2f(x)
#endif

__device__ __forceinline__ short8 load8(const bf16* p) {
  return *reinterpret_cast<const short8*>(p);
}
__device__ __forceinline__ short4b load4(const bf16* p) {
  return *reinterpret_cast<const short4b*>(p);
}
__device__ __forceinline__ short f2b(float f) {
  return __builtin_bit_cast(short, __float2bfloat16(f));
}
__device__ __forceinline__ unsigned int pk2(float a, float b) {
  return (unsigned int)(unsigned short)f2b(a) |
         ((unsigned int)(unsigned short)f2b(b) << 16);
}
__device__ __forceinline__ void asy16(const bf16* g, bf16* l) {
  __builtin_amdgcn_global_load_lds(
      (const __attribute__((address_space(1))) void*)g,
      (__attribute__((address_space(3))) void*)l, 16, 0, 0);
}

// ---------------- fused prep kernel ----------------
__global__ void k_prep(const float4* __restrict__ x, ushort4* __restrict__ xb,
                       const float* __restrict__ Wq, const float* __restrict__ Wk,
                       const float* __restrict__ Wv, const float* __restrict__ Wo,
                       bf16* __restrict__ Wcat, bf16* __restrict__ Wot,
                       const int4* __restrict__ m4,
                       unsigned long long* __restrict__ bits) {
  int blk = blockIdx.x;
  if (blk < 4096) {
    int i = blk * 256 + threadIdx.x;
    float4 v = x[i];
    ushort4 o;
    o.x = (unsigned short)f2b(v.x);
    o.y = (unsigned short)f2b(v.y);
    o.z = (unsigned short)f2b(v.z);
    o.w = (unsigned short)f2b(v.w);
    xb[i] = o;
  } else if (blk < 8192) {
    int t = (blk - 4096) * 256 + threadIdx.x;
    if (t < 786432) {
      int rr = t >> 9, d = t & 511;
      int which = rr >> 9;
      int hdk = rr & 511, h = hdk >> 6, dk = hdk & 63;
      const float* W = (which == 0) ? Wq : ((which == 1) ? Wk : Wv);
      float v = W[(h * 512 + d) * 64 + dk];
      if (which == 0) v *= 0.18033688011112042f;  // 0.125 * log2(e)
      Wcat[t] = __float2bfloat16(v);
    } else {
      int u = t - 786432;
      int e = u >> 9, hv = u & 511;
      Wot[u] = __float2bfloat16(Wo[hv * 512 + e]);
    }
  } else {
    int i = (blk - 8192) * 256 + threadIdx.x;
    int4 v = m4[i];
    unsigned int nib = (unsigned)(v.x != 0) | ((unsigned)(v.y != 0) << 1) |
                       ((unsigned)(v.z != 0) << 2) | ((unsigned)(v.w != 0) << 3);
    unsigned long long w = (unsigned long long)nib << (4 * (threadIdx.x & 15));
    w |= __shfl_xor(w, 1);
    w |= __shfl_xor(w, 2);
    w |= __shfl_xor(w, 4);
    w |= __shfl_xor(w, 8);
    if ((threadIdx.x & 15) == 0) bits[i >> 4] = w;
  }
}

// ---------------- 128x128 double-buffered GEMM core ----------------
__device__ __forceinline__ void gemm128(const bf16* __restrict__ A,
                                        const bf16* __restrict__ Bt,
                                        bf16* As, bf16* Bs,
                                        int rowBase, int colBase,
                                        f32x4 acc[4][4]) {
  const int tid = threadIdx.x;
  const int lane = tid & 63, w = tid >> 6;
  const int g = lane >> 4, r = lane & 15;

  auto stage = [&](int buf, int s) {
#pragma unroll
    for (int p = 0; p < 4; ++p) {
      int c = p * 256 + tid;
      int row = c >> 3, w8 = c & 7, sg = w8 ^ (row & 7);
      asy16(A + (size_t)(rowBase + row) * 512 + s * 64 + sg * 8,
            As + buf * 8192 + c * 8);
    }
#pragma unroll
    for (int p = 0; p < 4; ++p) {
      int c = p * 256 + tid;
      int row = c >> 3, w8 = c & 7, sg = w8 ^ (row & 7);
      asy16(Bt + (size_t)(colBase + row) * 512 + s * 64 + sg * 8,
            Bs + buf * 8192 + c * 8);
    }
  };

  stage(0, 0);
  int buf = 0;
  const int rbl = (w >> 1) * 64, cbl = (w & 1) * 64;
  for (int s = 0; s < 8; ++s) {
    __syncthreads();
    if (s < 7) stage(buf ^ 1, s + 1);
    const bf16* a0 = As + buf * 8192;
    const bf16* b0 = Bs + buf * 8192;
#pragma unroll
    for (int kk = 0; kk < 2; ++kk) {
      short8 af[4], bfr[4];
#pragma unroll
      for (int mt = 0; mt < 4; ++mt) {
        int row = rbl + mt * 16 + r;
        af[mt] = load8(a0 + (row * 8 + ((kk * 4 + g) ^ (row & 7))) * 8);
      }
#pragma unroll
      for (int nt = 0; nt < 4; ++nt) {
        int col = cbl + nt * 16 + r;
        bfr[nt] = load8(b0 + (col * 8 + ((kk * 4 + g) ^ (col & 7))) * 8);
      }
#pragma unroll
      for (int mt = 0; mt < 4; ++mt)
#pragma unroll
        for (int nt = 0; nt < 4; ++nt)
          acc[mt][nt] = __builtin_amdgcn_mfma_f32_16x16x32_bf16(
              af[mt], bfr[nt], acc[mt][nt], 0, 0, 0);
    }
    buf ^= 1;
  }
}

// Fused QKV projection
__global__ __launch_bounds__(256, 2) void k_proj_qkv(
    const bf16* __restrict__ Xb, const bf16* __restrict__ Wcat,
    bf16* __restrict__ Qb, bf16* __restrict__ Kb, bf16* __restrict__ Vt) {
  __shared__ __align__(16) bf16 As[2 * 8192];
  __shared__ __align__(16) bf16 Bs[2 * 8192];
  int rowBase = blockIdx.x * 128, colBase = blockIdx.y * 128;
  f32x4 acc[4][4] = {};
  gemm128(Xb, Wcat, As, Bs, rowBase, colBase, acc);
  const int lane = threadIdx.x & 63, w = threadIdx.x >> 6;
  const int g = lane >> 4, r = lane & 15;
#pragma unroll
  for (int mt = 0; mt < 4; ++mt) {
    int row0 = rowBase + (w >> 1) * 64 + mt * 16 + 4 * g;
    int b = row0 >> 11, n0 = row0 & 2047;
#pragma unroll
    for (int nt = 0; nt < 4; ++nt) {
      int col = colBase + (w & 1) * 64 + nt * 16 + r;
      if (col < 1024) {
        bf16* dst = (col < 512) ? Qb : Kb;
        int hh = (col >> 6) & 7, dk = col & 63;
        bf16* p0 = dst + ((size_t)(b * 8 + hh) * 2048 + n0) * 64 + dk;
#pragma unroll
        for (int rr = 0; rr < 4; ++rr)
          p0[rr * 64] = __float2bfloat16(acc[mt][nt][rr]);
      } else {
        int hdv = col - 1024;
        short4b pkv;
#pragma unroll
        for (int rr = 0; rr < 4; ++rr) pkv[rr] = f2b(acc[mt][nt][rr]);
        *reinterpret_cast<short4b*>(Vt + ((size_t)b * 512 + hdv) * 2048 + n0) = pkv;
      }
    }
  }
}

// Output projection
__global__ __launch_bounds__(256, 2) void k_proj_out(
    const bf16* __restrict__ O, const bf16* __restrict__ Wot,
    float* __restrict__ out) {
  __shared__ __align__(16) bf16 As[2 * 8192];
  __shared__ __align__(16) bf16 Bs[2 * 8192];
  int rowBase = blockIdx.x * 128, colBase = blockIdx.y * 128;
  f32x4 acc[4][4] = {};
  gemm128(O, Wot, As, Bs, rowBase, colBase, acc);
  const int lane = threadIdx.x & 63, w = threadIdx.x >> 6;
  const int g = lane >> 4, r = lane & 15;
#pragma unroll
  for (int mt = 0; mt < 4; ++mt) {
    int row0 = rowBase + (w >> 1) * 64 + mt * 16 + 4 * g;
#pragma unroll
    for (int nt = 0; nt < 4; ++nt) {
      int col = colBase + (w & 1) * 64 + nt * 16 + r;
#pragma unroll
      for (int rr = 0; rr < 4; ++rr)
        out[(size_t)(row0 + rr) * 512 + col] = acc[mt][nt][rr];
    }
  }
}

// ---------------- flash attention, software-pipelined K-loop ----------------
// grid 512 (XCD-swizzled bh x 16 qt-tiles of 128 rows), 256 thr = 4 waves,
// 32 q-rows/wave (2 subtiles). Triple-buffered LDS, staging 2 tiles ahead;
// QK(kt+1) issued before softmax(kt) so matrix pipe fills the VALU chain.
// Max-free exp2 softmax; l via MFMA row-sum (shuffle-free epilogue).
__global__ __launch_bounds__(256, 2) void k_attn(const bf16* __restrict__ Q,
    const bf16* __restrict__ K, const bf16* __restrict__ Vt,
    const unsigned long long* __restrict__ MB, bf16* __restrict__ O) {
  const int blin = blockIdx.x;
  const int j = blin >> 3;
  const int bh = (blin & 7) * 4 + (j >> 4);
  const int qt = j & 15;
  const int b = bh >> 3, h = bh & 7;
  const int tid = threadIdx.x;
  const int lane = tid & 63;
  const int wave = tid >> 6;
  const int g = lane >> 4, r = lane & 15;
  const int rx = r & 7;
  const int qbase = qt * 128 + wave * 32;

  __shared__ __align__(16) bf16 Kl[3][64 * 64];
  __shared__ __align__(16) bf16 Vl[3][64 * 64];

  const bf16* Kp = K + (size_t)bh * 2048 * 64;
  const bf16* Vp = Vt + (size_t)bh * 64 * 2048;

  short8 qf[2][2];
#pragma unroll
  for (int s = 0; s < 2; ++s) {
    const bf16* Qp = Q + ((size_t)bh * 2048 + qbase + s * 16 + r) * 64;
    qf[s][0] = load8(Qp + g * 8);
    qf[s][1] = load8(Qp + 32 + g * 8);
  }
  const unsigned long long* Mp0 = MB + ((size_t)b * 2048 + qbase + r) * 32;
  const unsigned long long* Mp1 = MB + ((size_t)b * 2048 + qbase + 16 + r) * 32;

  short8 ones;
#pragma unroll
  for (int i = 0; i < 8; ++i) ones[i] = (short)0x3F80;  // bf16 1.0

  f32x4 acc[2][4] = {};
  f32x4 acc_l[2] = {};

  auto stage = [&](int buf, int kt) {
    const bf16* Kg = Kp + kt * 4096;
    const bf16* Vg = Vp + kt * 64;
#pragma unroll
    for (int p = 0; p < 2; ++p) {
      int c = p * 256 + tid;
      int row = c >> 3, gr = c & 7, sg = gr ^ (row & 7);
      asy16(Kg + row * 64 + sg * 8, &Kl[buf][0] + c * 8);
    }
#pragma unroll
    for (int p = 0; p < 2; ++p) {
      int c = p * 256 + tid;
      int row = c >> 3, gr = c & 7, sg = gr ^ (row & 7);
      asy16(Vg + (size_t)row * 2048 + sg * 8, &Vl[buf][0] + c * 8);
    }
  };

  auto qk = [&](const bf16* kl, f32x4 stl[4][2]) {
#pragma unroll
    for (int kc = 0; kc < 4; ++kc) {
      const bf16* krow = kl + (kc * 16 + r) * 64;
      short8 kf0 = load8(krow + ((g) ^ rx) * 8);
      short8 kf1 = load8(krow + ((4 + g) ^ rx) * 8);
      f32x4 z0 = {};
      z0 = __builtin_amdgcn_mfma_f32_16x16x32_bf16(kf0, qf[0][0], z0, 0, 0, 0);
      stl[kc][0] = __builtin_amdgcn_mfma_f32_16x16x32_bf16(kf1, qf[0][1], z0, 0, 0, 0);
      f32x4 z1 = {};
      z1 = __builtin_amdgcn_mfma_f32_16x16x32_bf16(kf0, qf[1][0], z1, 0, 0, 0);
      stl[kc][1] = __builtin_amdgcn_mfma_f32_16x16x32_bf16(kf1, qf[1][1], z1, 0, 0, 0);
    }
  };

  // prologue: stage tiles 0 and 1; first QK
  stage(0, 0);
  stage(1, 1);
  unsigned long long mw0c = Mp0[0], mw1c = Mp1[0];
  __syncthreads();
  f32x4 st_cur[4][2];
  qk(&Kl[0][0], st_cur);

  int b_cur = 0, b_nxt = 1, b_st = 2;

  for (int kt = 0; kt < 32; ++kt) {
    __syncthreads();  // stage(kt+1) drained; readers of b_st's old tile done
    if (kt < 30) stage(b_st, kt + 2);
    unsigned long long mw0n = 0, mw1n = 0;
    if (kt < 31) { mw0n = Mp0[kt + 1]; mw1n = Mp1[kt + 1]; }

    // QK for kt+1 (independent of softmax(kt) -> overlaps VALU chain)
    f32x4 stn[4][2];
    if (kt < 31) qk(&Kl[b_nxt][0], stn);

    // softmax(kt): p = exp2(st), mask -> 0; l via MFMA row-sum
    short8 pa[2][2];
#pragma unroll
    for (int s = 0; s < 2; ++s) {
      unsigned long long mw = s ? mw1c : mw0c;
      unsigned ml = (unsigned)mw >> (4 * g);
      unsigned mh = (unsigned)(mw >> 32) >> (4 * g);
      float p[16];
#pragma unroll
      for (int kc = 0; kc < 4; ++kc)
#pragma unroll
        for (int rr = 0; rr < 4; ++rr) {
          float e = EXP2(st_cur[kc][s][rr]);
          unsigned wsel = (kc & 2) ? mh : ml;
          bool bad = (wsel >> (((kc & 1) << 4) + rr)) & 1u;
          p[kc * 4 + rr] = bad ? 0.f : e;
        }
      u32x4 q0, q1;
#pragma unroll
      for (int i2 = 0; i2 < 4; ++i2) {
        q0[i2] = pk2(p[2 * i2], p[2 * i2 + 1]);
        q1[i2] = pk2(p[8 + 2 * i2], p[8 + 2 * i2 + 1]);
      }
      pa[s][0] = __builtin_bit_cast(short8, q0);
      pa[s][1] = __builtin_bit_cast(short8, q1);
      acc_l[s] = __builtin_amdgcn_mfma_f32_16x16x32_bf16(pa[s][0], ones, acc_l[s], 0, 0, 0);
      acc_l[s] = __builtin_amdgcn_mfma_f32_16x16x32_bf16(pa[s][1], ones, acc_l[s], 0, 0, 0);
    }

    // PV(kt) with permuted contraction (V frags shared across subtiles)
    const bf16* vl = &Vl[b_cur][0];
#pragma unroll
    for (int dvs = 0; dvs < 4; ++dvs) {
      const bf16* vrow = vl + (dvs * 16 + r) * 64 + (g & 1) * 4;
      short4b v0 = load4(vrow + (((g >> 1)) ^ rx) * 8);
      short4b v1 = load4(vrow + ((2 + (g >> 1)) ^ rx) * 8);
      short4b v2 = load4(vrow + ((4 + (g >> 1)) ^ rx) * 8);
      short4b v3 = load4(vrow + ((6 + (g >> 1)) ^ rx) * 8);
      short8 vb0 = {v0[0], v0[1], v0[2], v0[3], v1[0], v1[1], v1[2], v1[3]};
      short8 vb1 = {v2[0], v2[1], v2[2], v2[3], v3[0], v3[1], v3[2], v3[3]};
#pragma unroll
      for (int s = 0; s < 2; ++s) {
        acc[s][dvs] = __builtin_amdgcn_mfma_f32_16x16x32_bf16(pa[s][0], vb0, acc[s][dvs], 0, 0, 0);
        acc[s][dvs] = __builtin_amdgcn_mfma_f32_16x16x32_bf16(pa[s][1], vb1, acc[s][dvs], 0, 0, 0);
      }
    }

    // rotate pipeline state
#pragma unroll
    for (int kc = 0; kc < 4; ++kc) {
      st_cur[kc][0] = stn[kc][0];
      st_cur[kc][1] = stn[kc][1];
    }
    mw0c = mw0n;
    mw1c = mw1n;
    int t = b_cur; b_cur = b_nxt; b_nxt = b_st; b_st = t;
  }

  // shuffle-free epilogue
#pragma unroll
  for (int s = 0; s < 2; ++s) {
    float inv[4];
#pragma unroll
    for (int rr = 0; rr < 4; ++rr)
      inv[rr] = (acc_l[s][rr] > 0.f) ? 1.f / acc_l[s][rr] : 0.f;
    bf16* Op = O + ((size_t)b * 2048 + qbase + s * 16 + 4 * g) * 512 + h * 64;
#pragma unroll
    for (int dvs = 0; dvs < 4; ++dvs)
#pragma unroll
      for (int rr = 0; rr < 4; ++rr)
        Op[rr * 512 + dvs * 16 + r] = __float2bfloat16(acc[s][dvs][rr] * inv[rr]);
  }
}

// ---------------- launch ----------------

extern "C" void kernel_launch(void* const* d_in, const int* in_sizes, int n_in,
                              void* d_out, int out_size, void* d_ws, size_t ws_size,
                              hipStream_t stream) {
  const float* q    = (const float*)d_in[0];
  const int*   mask = (const int*)d_in[1];
  const float* Wq   = (const float*)d_in[2];
  const float* Wk   = (const float*)d_in[3];
  const float* Wv   = (const float*)d_in[4];
  const float* Wo   = (const float*)d_in[5];
  float* out = (float*)d_out;

  char* ws = (char*)d_ws;
  const size_t MB1 = 1024 * 1024;
  bf16* Xb   = (bf16*)(ws + 0);
  bf16* Qb   = (bf16*)(ws + 8 * MB1);
  bf16* Kb   = (bf16*)(ws + 16 * MB1);
  bf16* Vtb  = (bf16*)(ws + 24 * MB1);
  bf16* Ob   = (bf16*)(ws + 32 * MB1);
  unsigned long long* Mbits = (unsigned long long*)(ws + 40 * MB1);
  bf16* Wcat = (bf16*)(ws + 42 * MB1);
  bf16* Wot  = (bf16*)(ws + 42 * MB1 + 1536 * 512 * 2);

  k_prep<<<24576, 256, 0, stream>>>((const float4*)q, (ushort4*)Xb,
                                    Wq, Wk, Wv, Wo, Wcat, Wot,
                                    (const int4*)mask, Mbits);
  k_proj_qkv<<<dim3(64, 12), 256, 0, stream>>>(Xb, Wcat, Qb, Kb, Vtb);
  k_attn<<<512, 256, 0, stream>>>(Qb, Kb, Vtb, Mbits, Ob);
  k_proj_out<<<dim3(64, 4), 256, 0, stream>>>(Ob, Wot, out);
}